// Round 12
// baseline (250.587 us; speedup 1.0000x reference)
//
#include <hip/hip_runtime.h>

typedef int   i32x4 __attribute__((ext_vector_type(4)));
typedef int   i32x8 __attribute__((ext_vector_type(8)));
typedef float f32x16 __attribute__((ext_vector_type(16)));

#define D_DIM 256
#define LOG2E 1.4426950408889634f
#define LN2   0.6931471805599453f
// k-major strip layout: [strip of 128 rows][kc16 0..15][row 0..127][16B]
#define STRIP_BYTES 32768
#define NBLK 4096     // (N/128 strips) x (N/512 col groups)

#if __has_builtin(__builtin_amdgcn_exp2f)
static __device__ __forceinline__ float exp2_fast(float x) { return __builtin_amdgcn_exp2f(x); }
#else
static __device__ __forceinline__ float exp2_fast(float x) { return __expf(x * LN2); }
#endif
#if __has_builtin(__builtin_amdgcn_logf)
static __device__ __forceinline__ float log2_fast(float x) { return __builtin_amdgcn_logf(x); }
#else
static __device__ __forceinline__ float log2_fast(float x) { return __logf(x) * LOG2E; }
#endif

#if __has_builtin(__builtin_amdgcn_cvt_pk_fp8_f32)
static __device__ __forceinline__ unsigned int pack4_fp8(float a, float b, float c, float d) {
    int v = 0;
    v = __builtin_amdgcn_cvt_pk_fp8_f32(a, b, v, false);
    v = __builtin_amdgcn_cvt_pk_fp8_f32(c, d, v, true);
    return (unsigned int)v;
}
#else
#include <hip/hip_fp8.h>
static __device__ __forceinline__ unsigned char cv1(float x) {
    __hip_fp8_e4m3 f(x);
    union { __hip_fp8_e4m3 f; unsigned char b; } u; u.f = f; return u.b;
}
static __device__ __forceinline__ unsigned int pack4_fp8(float a, float b, float c, float d) {
    return (unsigned int)cv1(a) | ((unsigned int)cv1(b) << 8) |
           ((unsigned int)cv1(c) << 16) | ((unsigned int)cv1(d) << 24);
}
#endif

// K=64 fp8 MFMA (32x32): MX-scaled if available, else 4x K=16 non-scaled.
static __device__ __forceinline__ f32x16 mfma_fp8_32x32_k64(i32x8 a, i32x8 b, f32x16 c) {
#if __has_builtin(__builtin_amdgcn_mfma_scale_f32_32x32x64_f8f6f4)
    return __builtin_amdgcn_mfma_scale_f32_32x32x64_f8f6f4(a, b, c, 0, 0, 0, 127, 0, 127);
#else
    union { i32x8 v; long l[4]; } ua, ub;
    ua.v = a; ub.v = b;
#pragma unroll
    for (int s = 0; s < 4; ++s)
        c = __builtin_amdgcn_mfma_f32_32x32x16_fp8_fp8(ua.l[s], ub.l[s], c, 0, 0, 0);
    return c;
#endif
}

// Kernel 1: L2-normalize fp32 -> fp8 e4m3 into k-major strips; zero counter.
__global__ __launch_bounds__(256) void norm_cast_kernel(
    const float* __restrict__ img, const float* __restrict__ txt,
    unsigned char* __restrict__ Ab, unsigned char* __restrict__ Bb,
    int* __restrict__ counter, int N)
{
    const int tid = threadIdx.x;
    const int q   = tid & 3;          // k-quarter (64 floats)
    const int rl  = tid >> 2;         // 0..63
    int gRow = blockIdx.x * 64 + rl;  // 0..2N-1

    const float* src;
    unsigned char* dstB;
    int row;
    if (gRow < N) { row = gRow;     src = img + (size_t)row * D_DIM; dstB = Ab; }
    else          { row = gRow - N; src = txt + (size_t)row * D_DIM; dstB = Bb; }

    float f[64];
    float ss = 0.0f;
    const float4* s4 = (const float4*)(src + q * 64);
#pragma unroll
    for (int i = 0; i < 16; ++i) {
        float4 v = s4[i];
        f[4*i+0] = v.x; f[4*i+1] = v.y; f[4*i+2] = v.z; f[4*i+3] = v.w;
        ss += v.x*v.x + v.y*v.y + v.z*v.z + v.w*v.w;
    }
    ss += __shfl_xor(ss, 1, 64);
    ss += __shfl_xor(ss, 2, 64);
    float inv = 1.0f / fmaxf(sqrtf(ss), 1e-12f);   // F.normalize eps

    unsigned char* dst = dstB + (size_t)(row >> 7) * STRIP_BYTES + (row & 127) * 16;
#pragma unroll
    for (int g = 0; g < 4; ++g) {
        const float* h = f + g * 16;
        uint4 w;
        w.x = pack4_fp8(h[ 0]*inv, h[ 1]*inv, h[ 2]*inv, h[ 3]*inv);
        w.y = pack4_fp8(h[ 4]*inv, h[ 5]*inv, h[ 6]*inv, h[ 7]*inv);
        w.z = pack4_fp8(h[ 8]*inv, h[ 9]*inv, h[10]*inv, h[11]*inv);
        w.w = pack4_fp8(h[12]*inv, h[13]*inv, h[14]*inv, h[15]*inv);
        *(uint4*)(dst + (q * 4 + g) * 2048) = w;   // kc = q*4+g
    }

    if (blockIdx.x == 0 && tid == 0) counter[0] = 0;
}

// Kernel 2: fp8-MX Gram + softplus-sum, warm-pipeline multi-tile blocks.
//  Block = 128 rows x 512 cols (4 sequential 128-col tiles). A strip (32 KB,
//  full K) resident in LDS, staged once. B: 8-KB K=64 chunks, double-buffered,
//  16 chunks per block -> 16 barriers, each prefetch-covered. Per-tile
//  epilogue runs in the next tile's B-prefetch shadow.
//  R11 FIX: compute-chunk stride in the A strip is 8192 B (4 kc16 x 2048),
//  was wrongly 16384 -> OOB reads of NaN-pattern fp8 for c=2,3.
__global__ __launch_bounds__(256, 3) void siglip_loss_kernel(
    const unsigned char* __restrict__ A, const unsigned char* __restrict__ B,
    const float* __restrict__ t_prime, const float* __restrict__ bias,
    float* __restrict__ partials, int* __restrict__ counter,
    float* __restrict__ out, int N)
{
    __shared__ unsigned char AsR[32768];    // [kc16 0..15][row 0..127][16B]
    __shared__ unsigned char Bs[2][8192];   // [kc16 0..3][row 0..127][16B]
    __shared__ float red[4];
    __shared__ int  isLast;

    const int tid  = threadIdx.x;
    const int wave = tid >> 6;
    const int lane = tid & 63;
    const int r31  = lane & 31;
    const int g    = lane >> 5;       // k-group within chunk (2 kc16 each)
    const int wv   = wave >> 1;       // 0..1 row half (64)
    const int wu   = wave & 1;        // 0..1 col half (64)

    const int bid = blockIdx.x;
    const int by  = bid & 127;        // row strip
    const int bxg = bid >> 7;         // col group (4 strips of 128)

    const unsigned char* Astrip = A + (size_t)by * STRIP_BYTES;
    const unsigned char* Bbase  = B + (size_t)(bxg * 4) * STRIP_BYTES;

    // ---- stage A strip once: 32 x 1KB contiguous loads (8 per wave)
#pragma unroll
    for (int l = 0; l < 8; ++l) {
        int idx = wave * 8 + l;
        __builtin_amdgcn_global_load_lds(
            (const __attribute__((address_space(1))) unsigned int*)(Astrip + idx * 1024 + lane * 16),
            (__attribute__((address_space(3))) unsigned int*)&AsR[idx * 1024],
            16, 0, 0);
    }

    // stage B chunk c (8 KB) of tile t into buffer buf
    auto stageB = [&](int buf, int t, int c) {
        const unsigned char* gb = Bbase + (size_t)t * STRIP_BYTES + c * 8192;
#pragma unroll
        for (int l = 0; l < 2; ++l) {
            int idx = wave * 2 + l;
            __builtin_amdgcn_global_load_lds(
                (const __attribute__((address_space(1))) unsigned int*)(gb + idx * 1024 + lane * 16),
                (__attribute__((address_space(3))) unsigned int*)&Bs[buf][idx * 1024],
                16, 0, 0);
        }
    };

    stageB(0, 0, 0);

    // fragment base offsets (bytes) within one 8-KB K=64 chunk
    int a_base[2], b_base[2];
#pragma unroll
    for (int i = 0; i < 2; ++i)
        a_base[i] = (g * 2 * 128 + wv * 64 + i * 32 + r31) * 16;
#pragma unroll
    for (int j = 0; j < 2; ++j)
        b_base[j] = (g * 2 * 128 + wu * 64 + j * 32 + r31) * 16;

    const float s2 = __expf(t_prime[0]) * LOG2E;
    const float b2 = bias[0] * LOG2E;
    float local = 0.0f;
    union F { i32x8 v8; i32x4 v4[2]; };

#pragma unroll 1
    for (int t = 0; t < 4; ++t) {
        f32x16 acc[2][2];
#pragma unroll
        for (int c = 0; c < 4; ++c) {
            const int k = t * 4 + c;           // global chunk 0..15
            __syncthreads();                   // publishes Bs[k&1] (and AsR @k=0)
            if (c < 3)      stageB((k + 1) & 1, t, c + 1);
            else if (t < 3) stageB((k + 1) & 1, t + 1, 0);

            const unsigned char* as = &AsR[c * 8192];   // FIX: was c*16384 (OOB)
            const unsigned char* bs = Bs[k & 1];
            F a[2], b[2];
#pragma unroll
            for (int i = 0; i < 2; ++i) {
                a[i].v4[0] = *(const i32x4*)&as[a_base[i]];
                a[i].v4[1] = *(const i32x4*)&as[a_base[i] + 2048];
                b[i].v4[0] = *(const i32x4*)&bs[b_base[i]];
                b[i].v4[1] = *(const i32x4*)&bs[b_base[i] + 2048];
            }
#pragma unroll
            for (int i = 0; i < 2; ++i)
#pragma unroll
                for (int j = 0; j < 2; ++j) {
                    f32x16 cin = (c == 0) ? f32x16{} : acc[i][j];
                    acc[i][j] = mfma_fp8_32x32_k64(a[i].v8, b[j].v8, cin);
                }
        }

        // ---- per-tile epilogue (register-only; next B prefetch in flight)
#pragma unroll
        for (int i = 0; i < 2; ++i)
#pragma unroll
            for (int j = 0; j < 2; ++j)
#pragma unroll
                for (int g2 = 0; g2 < 2; ++g2) {
                    float x[8];
#pragma unroll
                    for (int e = 0; e < 8; ++e)
                        x[e] = exp2_fast(fmaf(s2, acc[i][j][g2 * 8 + e], b2));
                    float p = 1.0f + x[0];
#pragma unroll
                    for (int e = 1; e < 8; ++e)
                        p = fmaf(p, x[e], p);      // p *= (1 + x[e])
                    local += log2_fast(p);
                }

        // diagonal tile: softplus(-z) = softplus(z) - z  -> subtract z2
        if (bxg * 4 + t == by) {
#pragma unroll
            for (int i = 0; i < 2; ++i)
#pragma unroll
                for (int j = 0; j < 2; ++j)
#pragma unroll
                    for (int r = 0; r < 16; ++r) {
                        // 32x32 C/D (m74/m101): col=lane&31, row=(r&3)+8*(r>>2)+4*g
                        int rowf = (r & 3) + 8 * (r >> 2) + 4 * g;
                        int grow = wv * 64 + i * 32 + rowf;
                        int gcol = wu * 64 + j * 32 + r31;
                        if (grow == gcol) local -= fmaf(s2, acc[i][j][r], b2);
                    }
        }
    }

    // ---- block reduction + completion-counter final reduce
#pragma unroll
    for (int off = 32; off > 0; off >>= 1)
        local += __shfl_xor(local, off, 64);
    if (lane == 0) red[wave] = local;
    __syncthreads();
    if (tid == 0) {
        partials[bid] = (red[0] + red[1]) + (red[2] + red[3]);
        __threadfence();                         // release partial
        int old = atomicAdd(counter, 1);         // device-scope
        isLast = (old == NBLK - 1) ? 1 : 0;
    }
    __syncthreads();
    if (isLast) {
        __threadfence();                         // acquire all partials
        float s = 0.0f;
        for (int i = tid; i < NBLK; i += 256)
            s += ((volatile const float*)partials)[i];
#pragma unroll
        for (int off = 32; off > 0; off >>= 1)
            s += __shfl_xor(s, off, 64);
        if (lane == 0) red[wave] = s;
        __syncthreads();
        if (tid == 0)
            out[0] = ((red[0] + red[1]) + (red[2] + red[3])) * (LN2 / (float)N);
    }
}

extern "C" void kernel_launch(void* const* d_in, const int* in_sizes, int n_in,
                              void* d_out, int out_size, void* d_ws, size_t ws_size,
                              hipStream_t stream) {
    const float* img = (const float*)d_in[0];
    const float* txt = (const float*)d_in[1];
    const float* tp  = (const float*)d_in[2];
    const float* bs  = (const float*)d_in[3];
    float* out = (float*)d_out;
    int N = in_sizes[0] / D_DIM;    // 16384

    unsigned char* Ab = (unsigned char*)d_ws;       // 4 MB (k-major strips)
    unsigned char* Bb = Ab + (size_t)N * D_DIM;     // +4 MB
    float* partials   = (float*)(Bb + (size_t)N * D_DIM);   // 16 KB
    int*   counter    = (int*)(partials + NBLK);

    norm_cast_kernel<<<(2 * N) / 64, 256, 0, stream>>>(img, txt, Ab, Bb, counter, N);
    siglip_loss_kernel<<<NBLK, 256, 0, stream>>>(Ab, Bb, tp, bs, partials, counter, out, N);
}

// Round 13
// 182.891 us; speedup vs baseline: 1.3701x; 1.3701x over previous
//
#include <hip/hip_runtime.h>

typedef int   i32x4 __attribute__((ext_vector_type(4)));
typedef int   i32x8 __attribute__((ext_vector_type(8)));
typedef float f32x16 __attribute__((ext_vector_type(16)));

#define D_DIM 256
#define LOG2E 1.4426950408889634f
#define LN2   0.6931471805599453f
// k-major strip layout: [strip of 128 rows][kc16 0..15][row 0..127][16B]
#define STRIP_BYTES 32768
#define NBLK 16384
#define NPART (NBLK * 4)   // one partial per wave

#if __has_builtin(__builtin_amdgcn_exp2f)
static __device__ __forceinline__ float exp2_fast(float x) { return __builtin_amdgcn_exp2f(x); }
#else
static __device__ __forceinline__ float exp2_fast(float x) { return __expf(x * LN2); }
#endif
#if __has_builtin(__builtin_amdgcn_logf)
static __device__ __forceinline__ float log2_fast(float x) { return __builtin_amdgcn_logf(x); }
#else
static __device__ __forceinline__ float log2_fast(float x) { return __logf(x) * LOG2E; }
#endif

#if __has_builtin(__builtin_amdgcn_cvt_pk_fp8_f32)
static __device__ __forceinline__ unsigned int pack4_fp8(float a, float b, float c, float d) {
    int v = 0;
    v = __builtin_amdgcn_cvt_pk_fp8_f32(a, b, v, false);
    v = __builtin_amdgcn_cvt_pk_fp8_f32(c, d, v, true);
    return (unsigned int)v;
}
#else
#include <hip/hip_fp8.h>
static __device__ __forceinline__ unsigned char cv1(float x) {
    __hip_fp8_e4m3 f(x);
    union { __hip_fp8_e4m3 f; unsigned char b; } u; u.f = f; return u.b;
}
static __device__ __forceinline__ unsigned int pack4_fp8(float a, float b, float c, float d) {
    return (unsigned int)cv1(a) | ((unsigned int)cv1(b) << 8) |
           ((unsigned int)cv1(c) << 16) | ((unsigned int)cv1(d) << 24);
}
#endif

// K=64 fp8 MFMA (32x32): MX-scaled if available, else 4x K=16 non-scaled.
static __device__ __forceinline__ f32x16 mfma_fp8_32x32_k64(i32x8 a, i32x8 b, f32x16 c) {
#if __has_builtin(__builtin_amdgcn_mfma_scale_f32_32x32x64_f8f6f4)
    return __builtin_amdgcn_mfma_scale_f32_32x32x64_f8f6f4(a, b, c, 0, 0, 0, 127, 0, 127);
#else
    union { i32x8 v; long l[4]; } ua, ub;
    ua.v = a; ub.v = b;
#pragma unroll
    for (int s = 0; s < 4; ++s)
        c = __builtin_amdgcn_mfma_f32_32x32x16_fp8_fp8(ua.l[s], ub.l[s], c, 0, 0, 0);
    return c;
#endif
}

// Kernel 1: L2-normalize fp32 -> fp8 e4m3 into k-major strips.
__global__ __launch_bounds__(256) void norm_cast_kernel(
    const float* __restrict__ img, const float* __restrict__ txt,
    unsigned char* __restrict__ Ab, unsigned char* __restrict__ Bb, int N)
{
    const int tid = threadIdx.x;
    const int q   = tid & 3;          // k-quarter (64 floats)
    const int rl  = tid >> 2;         // 0..63
    int gRow = blockIdx.x * 64 + rl;  // 0..2N-1

    const float* src;
    unsigned char* dstB;
    int row;
    if (gRow < N) { row = gRow;     src = img + (size_t)row * D_DIM; dstB = Ab; }
    else          { row = gRow - N; src = txt + (size_t)row * D_DIM; dstB = Bb; }

    float f[64];
    float ss = 0.0f;
    const float4* s4 = (const float4*)(src + q * 64);
#pragma unroll
    for (int i = 0; i < 16; ++i) {
        float4 v = s4[i];
        f[4*i+0] = v.x; f[4*i+1] = v.y; f[4*i+2] = v.z; f[4*i+3] = v.w;
        ss += v.x*v.x + v.y*v.y + v.z*v.z + v.w*v.w;
    }
    ss += __shfl_xor(ss, 1, 64);
    ss += __shfl_xor(ss, 2, 64);
    float inv = 1.0f / fmaxf(sqrtf(ss), 1e-12f);   // F.normalize eps

    unsigned char* dst = dstB + (size_t)(row >> 7) * STRIP_BYTES + (row & 127) * 16;
#pragma unroll
    for (int g = 0; g < 4; ++g) {
        const float* h = f + g * 16;
        uint4 w;
        w.x = pack4_fp8(h[ 0]*inv, h[ 1]*inv, h[ 2]*inv, h[ 3]*inv);
        w.y = pack4_fp8(h[ 4]*inv, h[ 5]*inv, h[ 6]*inv, h[ 7]*inv);
        w.z = pack4_fp8(h[ 8]*inv, h[ 9]*inv, h[10]*inv, h[11]*inv);
        w.w = pack4_fp8(h[12]*inv, h[13]*inv, h[14]*inv, h[15]*inv);
        *(uint4*)(dst + (q * 4 + g) * 2048) = w;   // kc = q*4+g
    }
}

// Kernel 2: fp8-MX Gram + softplus-sum (R10 structure, verified 103 us).
//  Tile 128x128, 4 waves (2x2), wave 64x64 = 2x2 of 32x32x64 MX MFMA.
//  K = 256 as 4 chunks of 64; LDS = dbuf (A 8KB + B 8KB) x2 = EXACTLY 32768 B
//  (no shared red array) -> 5 blocks/CU at 160 KB LDS; launch_bounds(256,5).
//  Fragment reads: (kc*128+row)*16 -> 8 consecutive lanes cover all 32 banks
//  once -> conflict-free (R10-verified 0). Reduction: per-WAVE partial store
//  (shuffle-reduce + lane0 store, no LDS, no barrier, no atomics).
__global__ __launch_bounds__(256, 5) void siglip_loss_kernel(
    const unsigned char* __restrict__ A, const unsigned char* __restrict__ B,
    const float* __restrict__ t_prime, const float* __restrict__ bias,
    float* __restrict__ partials, int N)
{
    __shared__ unsigned char As[2][8192];   // [kc16 0..3][row 0..127][16B]
    __shared__ unsigned char Bs[2][8192];

    const int tid  = threadIdx.x;
    const int wave = tid >> 6;
    const int lane = tid & 63;
    const int r31  = lane & 31;
    const int g    = lane >> 5;       // k-group (2 kc16 chunks of the 4)
    const int wv   = wave >> 1;       // 0..1 row half
    const int wu   = wave & 1;        // 0..1 col half

    // 16x16 supertile swizzle for L2 locality (grid 16384 flat).
    const int bid = blockIdx.x;
    const int st  = bid >> 8;
    const int l2  = bid & 255;
    const int bx  = (st & 7) * 16 + (l2 & 15);
    const int by  = (st >> 3) * 16 + (l2 >> 4);
    const int rowBase = by * 128;
    const int colBase = bx * 128;

    const unsigned char* Astrip = A + (size_t)by * STRIP_BYTES;
    const unsigned char* Bstrip = B + (size_t)bx * STRIP_BYTES;

    // Stage K-chunk c (8 KB per operand = 8 x 1KB loads, 2 per wave each).
    auto stage = [&](int buf, int c) {
        const unsigned char* ga = Astrip + c * 8192;
        const unsigned char* gb = Bstrip + c * 8192;
#pragma unroll
        for (int l = 0; l < 2; ++l) {
            int idx = wave * 2 + l;   // 0..7
            __builtin_amdgcn_global_load_lds(
                (const __attribute__((address_space(1))) unsigned int*)(ga + idx * 1024 + lane * 16),
                (__attribute__((address_space(3))) unsigned int*)&As[buf][idx * 1024],
                16, 0, 0);
            __builtin_amdgcn_global_load_lds(
                (const __attribute__((address_space(1))) unsigned int*)(gb + idx * 1024 + lane * 16),
                (__attribute__((address_space(3))) unsigned int*)&Bs[buf][idx * 1024],
                16, 0, 0);
        }
    };

    stage(0, 0);

    // Fragment LDS offsets: kc_local = 2g (+1 for the second 16B half).
    int a_off[2], b_off[2];
#pragma unroll
    for (int i = 0; i < 2; ++i) a_off[i] = g * 4096 + (wv * 64 + i * 32 + r31) * 16;
#pragma unroll
    for (int j = 0; j < 2; ++j) b_off[j] = g * 4096 + (wu * 64 + j * 32 + r31) * 16;

    f32x16 acc[2][2] = {};
    union F { i32x8 v8; i32x4 v4[2]; };

#pragma unroll 1
    for (int c = 0; c < 4; ++c) {
        __syncthreads();                    // publishes buffer c&1
        if (c < 3) stage((c + 1) & 1, c + 1);

        const unsigned char* as = As[c & 1];
        const unsigned char* bs = Bs[c & 1];
        F a[2], b[2];
#pragma unroll
        for (int i = 0; i < 2; ++i) {
            a[i].v4[0] = *(const i32x4*)&as[a_off[i]];
            a[i].v4[1] = *(const i32x4*)&as[a_off[i] + 2048];
            b[i].v4[0] = *(const i32x4*)&bs[b_off[i]];
            b[i].v4[1] = *(const i32x4*)&bs[b_off[i] + 2048];
        }
#pragma unroll
        for (int i = 0; i < 2; ++i)
#pragma unroll
            for (int j = 0; j < 2; ++j)
                acc[i][j] = mfma_fp8_32x32_k64(a[i].v8, b[j].v8, acc[i][j]);
    }

    // Epilogue: z2 = s2*acc + b2 (log2 domain); log2 of products of 8.
    const float s2 = __expf(t_prime[0]) * LOG2E;
    const float b2 = bias[0] * LOG2E;
    float local = 0.0f;
#pragma unroll
    for (int i = 0; i < 2; ++i)
#pragma unroll
        for (int j = 0; j < 2; ++j)
#pragma unroll
            for (int g2 = 0; g2 < 2; ++g2) {
                float x[8];
#pragma unroll
                for (int e = 0; e < 8; ++e)
                    x[e] = exp2_fast(fmaf(s2, acc[i][j][g2 * 8 + e], b2));
                float p = 1.0f + x[0];
#pragma unroll
                for (int e = 1; e < 8; ++e)
                    p = fmaf(p, x[e], p);      // p *= (1 + x[e])
                local += log2_fast(p);
            }

    // Diagonal blocks: softplus(-z) = softplus(z) - z -> subtract z2.
    if (rowBase == colBase) {
#pragma unroll
        for (int i = 0; i < 2; ++i)
#pragma unroll
            for (int j = 0; j < 2; ++j)
#pragma unroll
                for (int r = 0; r < 16; ++r) {
                    // 32x32 C/D layout (m74/m101): col = lane&31,
                    // row = (r&3) + 8*(r>>2) + 4*(lane>>5)
                    int rowf = (r & 3) + 8 * (r >> 2) + 4 * g;
                    int grow = wv * 64 + i * 32 + rowf;
                    int gcol = wu * 64 + j * 32 + r31;
                    if (grow == gcol) local -= fmaf(s2, acc[i][j][r], b2);
                }
    }

    // Per-WAVE partial: shuffle-reduce, lane0 stores. No LDS, no barrier.
#pragma unroll
    for (int off = 32; off > 0; off >>= 1)
        local += __shfl_xor(local, off, 64);
    if (lane == 0)
        partials[bid * 4 + wave] = local;
}

// Kernel 3: reduce 65536 per-wave partials -> out[0]. One block, ~4 us.
__global__ __launch_bounds__(1024) void reduce_kernel(
    const float* __restrict__ partials, float* __restrict__ out, int N)
{
    __shared__ float red[16];
    const int tid  = threadIdx.x;
    const int wave = tid >> 6;
    const int lane = tid & 63;
    float s = 0.0f;
#pragma unroll 4
    for (int i = tid; i < NPART; i += 1024)
        s += partials[i];
#pragma unroll
    for (int off = 32; off > 0; off >>= 1)
        s += __shfl_xor(s, off, 64);
    if (lane == 0) red[wave] = s;
    __syncthreads();
    if (tid == 0) {
        float t = 0.0f;
#pragma unroll
        for (int w = 0; w < 16; ++w) t += red[w];
        out[0] = t * (LN2 / (float)N);
    }
}

extern "C" void kernel_launch(void* const* d_in, const int* in_sizes, int n_in,
                              void* d_out, int out_size, void* d_ws, size_t ws_size,
                              hipStream_t stream) {
    const float* img = (const float*)d_in[0];
    const float* txt = (const float*)d_in[1];
    const float* tp  = (const float*)d_in[2];
    const float* bs  = (const float*)d_in[3];
    float* out = (float*)d_out;
    int N = in_sizes[0] / D_DIM;    // 16384

    unsigned char* Ab = (unsigned char*)d_ws;       // 4 MB (k-major strips)
    unsigned char* Bb = Ab + (size_t)N * D_DIM;     // +4 MB
    float* partials   = (float*)(Bb + (size_t)N * D_DIM);   // 256 KB

    norm_cast_kernel<<<(2 * N) / 64, 256, 0, stream>>>(img, txt, Ab, Bb, N);
    siglip_loss_kernel<<<NBLK, 256, 0, stream>>>(Ab, Bb, tp, bs, partials, N);
    reduce_kernel<<<1, 1024, 0, stream>>>(partials, out, N);
}

// Round 14
// 168.056 us; speedup vs baseline: 1.4911x; 1.0883x over previous
//
#include <hip/hip_runtime.h>

typedef int   i32x4 __attribute__((ext_vector_type(4)));
typedef int   i32x8 __attribute__((ext_vector_type(8)));
typedef float f32x16 __attribute__((ext_vector_type(16)));

#define D_DIM 256
#define LOG2E 1.4426950408889634f
#define LN2   0.6931471805599453f
// k-major strip layout: [strip of 128 rows][kc16 0..15][row 0..127][16B]
#define STRIP_BYTES 32768
#define NBLK 16384
#define NPART (NBLK * 4)   // one partial per wave

#if __has_builtin(__builtin_amdgcn_exp2f)
static __device__ __forceinline__ float exp2_fast(float x) { return __builtin_amdgcn_exp2f(x); }
#else
static __device__ __forceinline__ float exp2_fast(float x) { return __expf(x * LN2); }
#endif
#if __has_builtin(__builtin_amdgcn_logf)
static __device__ __forceinline__ float log2_fast(float x) { return __builtin_amdgcn_logf(x); }
#else
static __device__ __forceinline__ float log2_fast(float x) { return __logf(x) * LOG2E; }
#endif

#if __has_builtin(__builtin_amdgcn_cvt_pk_fp8_f32)
static __device__ __forceinline__ unsigned int pack4_fp8(float a, float b, float c, float d) {
    int v = 0;
    v = __builtin_amdgcn_cvt_pk_fp8_f32(a, b, v, false);
    v = __builtin_amdgcn_cvt_pk_fp8_f32(c, d, v, true);
    return (unsigned int)v;
}
#else
#include <hip/hip_fp8.h>
static __device__ __forceinline__ unsigned char cv1(float x) {
    __hip_fp8_e4m3 f(x);
    union { __hip_fp8_e4m3 f; unsigned char b; } u; u.f = f; return u.b;
}
static __device__ __forceinline__ unsigned int pack4_fp8(float a, float b, float c, float d) {
    return (unsigned int)cv1(a) | ((unsigned int)cv1(b) << 8) |
           ((unsigned int)cv1(c) << 16) | ((unsigned int)cv1(d) << 24);
}
#endif

// K=64 fp8 MFMA (32x32): MX-scaled if available, else 4x K=16 non-scaled.
static __device__ __forceinline__ f32x16 mfma_fp8_32x32_k64(i32x8 a, i32x8 b, f32x16 c) {
#if __has_builtin(__builtin_amdgcn_mfma_scale_f32_32x32x64_f8f6f4)
    return __builtin_amdgcn_mfma_scale_f32_32x32x64_f8f6f4(a, b, c, 0, 0, 0, 127, 0, 127);
#else
    union { i32x8 v; long l[4]; } ua, ub;
    ua.v = a; ub.v = b;
#pragma unroll
    for (int s = 0; s < 4; ++s)
        c = __builtin_amdgcn_mfma_f32_32x32x16_fp8_fp8(ua.l[s], ub.l[s], c, 0, 0, 0);
    return c;
#endif
}

// Kernel 1 v2: L2-normalize fp32 -> fp8 e4m3 into k-major strips, with LDS
// transpose so BOTH global phases are coalesced (old version scattered 16-B
// stores at 2048-B stride — ~49 us; this should be ~10 us).
// Block = 256 thr, 64 rows. Phase 1: pass p, wave w reads row p*4+w as a
// coalesced 1-KB float4 load, shuffle-reduces ss, packs fp8, stores 4 B/lane
// to LDS at chunk-swizzled (kc ^ (rl&15)) position (2-way banks = free).
// Phase 2: 4 coalesced 4-KB passes; ds_read_b128 covers 32 banks/8 lanes.
__global__ __launch_bounds__(256) void norm_cast_kernel(
    const float* __restrict__ img, const float* __restrict__ txt,
    unsigned char* __restrict__ Ab, unsigned char* __restrict__ Bb, int N)
{
    __shared__ unsigned char S[64 * 256];   // 16 KB
    const int tid  = threadIdx.x;
    const int wave = tid >> 6;
    const int lane = tid & 63;

    int gRow0 = blockIdx.x * 64;            // 0..2N-1
    const float* srcM;
    unsigned char* dstM;
    int base;
    if (gRow0 < N) { srcM = img; dstM = Ab; base = gRow0; }
    else           { srcM = txt; dstM = Bb; base = gRow0 - N; }

#pragma unroll
    for (int p = 0; p < 16; ++p) {
        int rl = p * 4 + wave;               // local row 0..63
        float4 v = ((const float4*)(srcM + (size_t)(base + rl) * D_DIM))[lane];
        float ss = v.x * v.x + v.y * v.y + v.z * v.z + v.w * v.w;
#pragma unroll
        for (int off = 32; off > 0; off >>= 1)
            ss += __shfl_xor(ss, off, 64);
        float inv = 1.0f / fmaxf(sqrtf(ss), 1e-12f);   // F.normalize eps
        unsigned int w4 = pack4_fp8(v.x * inv, v.y * inv, v.z * inv, v.w * inv);
        int kc   = lane >> 2;                // logical 16-B chunk 0..15
        int phys = kc ^ (rl & 15);           // swizzled position
        *(unsigned int*)&S[rl * 256 + phys * 16 + (lane & 3) * 4] = w4;
    }
    __syncthreads();

    int strip   = base >> 7;
    int rowHalf = base & 127;                // 0 or 64
    unsigned char* dstStrip = dstM + (size_t)strip * STRIP_BYTES;
#pragma unroll
    for (int q = 0; q < 4; ++q) {
        int lin = q * 4096 + tid * 16;       // [kc 0..15][row 0..63][16B]
        int kc  = lin >> 10;
        int rl  = (lin >> 4) & 63;
        uint4 w = *(const uint4*)&S[rl * 256 + (kc ^ (rl & 15)) * 16];
        *(uint4*)(dstStrip + kc * 2048 + (rowHalf + rl) * 16) = w;
    }
}

// Kernel 2: fp8-MX Gram + softplus-sum — R10 structure (verified 103 us).
//  Tile 128x128, 4 waves (2x2), wave 64x64 = 2x2 of 32x32x64 MX MFMA.
//  K = 256 as 4 chunks of 64; LDS = dbuf (A 8KB + B 8KB) x2 = 32768 B.
//  launch_bounds(256,4): R13's (256,5) capped regs at ~102 < acc+frag needs
//  -> 52 MB scratch spill; 4 waves/SIMD is the register ceiling here.
//  Reduction: per-WAVE partial store (shuffle + lane0 store; no atomics —
//  16384 same-address atomics serialize at ~13 ns = 215 us floor, R9->R10).
__global__ __launch_bounds__(256, 4) void siglip_loss_kernel(
    const unsigned char* __restrict__ A, const unsigned char* __restrict__ B,
    const float* __restrict__ t_prime, const float* __restrict__ bias,
    float* __restrict__ partials, int N)
{
    __shared__ unsigned char As[2][8192];   // [kc16 0..3][row 0..127][16B]
    __shared__ unsigned char Bs[2][8192];

    const int tid  = threadIdx.x;
    const int wave = tid >> 6;
    const int lane = tid & 63;
    const int r31  = lane & 31;
    const int g    = lane >> 5;       // k-group (2 kc16 chunks of the 4)
    const int wv   = wave >> 1;       // 0..1 row half
    const int wu   = wave & 1;        // 0..1 col half

    // 16x16 supertile swizzle for L2 locality (grid 16384 flat).
    const int bid = blockIdx.x;
    const int st  = bid >> 8;
    const int l2  = bid & 255;
    const int bx  = (st & 7) * 16 + (l2 & 15);
    const int by  = (st >> 3) * 16 + (l2 >> 4);
    const int rowBase = by * 128;
    const int colBase = bx * 128;

    const unsigned char* Astrip = A + (size_t)by * STRIP_BYTES;
    const unsigned char* Bstrip = B + (size_t)bx * STRIP_BYTES;

    auto stage = [&](int buf, int c) {
        const unsigned char* ga = Astrip + c * 8192;
        const unsigned char* gb = Bstrip + c * 8192;
#pragma unroll
        for (int l = 0; l < 2; ++l) {
            int idx = wave * 2 + l;   // 0..7
            __builtin_amdgcn_global_load_lds(
                (const __attribute__((address_space(1))) unsigned int*)(ga + idx * 1024 + lane * 16),
                (__attribute__((address_space(3))) unsigned int*)&As[buf][idx * 1024],
                16, 0, 0);
            __builtin_amdgcn_global_load_lds(
                (const __attribute__((address_space(1))) unsigned int*)(gb + idx * 1024 + lane * 16),
                (__attribute__((address_space(3))) unsigned int*)&Bs[buf][idx * 1024],
                16, 0, 0);
        }
    };

    stage(0, 0);

    int a_off[2], b_off[2];
#pragma unroll
    for (int i = 0; i < 2; ++i) a_off[i] = g * 4096 + (wv * 64 + i * 32 + r31) * 16;
#pragma unroll
    for (int j = 0; j < 2; ++j) b_off[j] = g * 4096 + (wu * 64 + j * 32 + r31) * 16;

    f32x16 acc[2][2] = {};
    union F { i32x8 v8; i32x4 v4[2]; };

#pragma unroll 1
    for (int c = 0; c < 4; ++c) {
        __syncthreads();                    // publishes buffer c&1
        if (c < 3) stage((c + 1) & 1, c + 1);

        const unsigned char* as = As[c & 1];
        const unsigned char* bs = Bs[c & 1];
        F a[2], b[2];
#pragma unroll
        for (int i = 0; i < 2; ++i) {
            a[i].v4[0] = *(const i32x4*)&as[a_off[i]];
            a[i].v4[1] = *(const i32x4*)&as[a_off[i] + 2048];
            b[i].v4[0] = *(const i32x4*)&bs[b_off[i]];
            b[i].v4[1] = *(const i32x4*)&bs[b_off[i] + 2048];
        }
#pragma unroll
        for (int i = 0; i < 2; ++i)
#pragma unroll
            for (int j = 0; j < 2; ++j)
                acc[i][j] = mfma_fp8_32x32_k64(a[i].v8, b[j].v8, acc[i][j]);
    }

    // Epilogue: z2 = s2*acc + b2 (log2 domain); log2 of products of 8.
    const float s2 = __expf(t_prime[0]) * LOG2E;
    const float b2 = bias[0] * LOG2E;
    float local = 0.0f;
#pragma unroll
    for (int i = 0; i < 2; ++i)
#pragma unroll
        for (int j = 0; j < 2; ++j)
#pragma unroll
            for (int g2 = 0; g2 < 2; ++g2) {
                float x[8];
#pragma unroll
                for (int e = 0; e < 8; ++e)
                    x[e] = exp2_fast(fmaf(s2, acc[i][j][g2 * 8 + e], b2));
                float p = 1.0f + x[0];
#pragma unroll
                for (int e = 1; e < 8; ++e)
                    p = fmaf(p, x[e], p);      // p *= (1 + x[e])
                local += log2_fast(p);
            }

    // Diagonal blocks: softplus(-z) = softplus(z) - z -> subtract z2.
    if (rowBase == colBase) {
#pragma unroll
        for (int i = 0; i < 2; ++i)
#pragma unroll
            for (int j = 0; j < 2; ++j)
#pragma unroll
                for (int r = 0; r < 16; ++r) {
                    // 32x32 C/D layout (m74/m101): col = lane&31,
                    // row = (r&3) + 8*(r>>2) + 4*(lane>>5)
                    int rowf = (r & 3) + 8 * (r >> 2) + 4 * g;
                    int grow = wv * 64 + i * 32 + rowf;
                    int gcol = wu * 64 + j * 32 + r31;
                    if (grow == gcol) local -= fmaf(s2, acc[i][j][r], b2);
                }
    }

    // Per-WAVE partial: shuffle-reduce, lane0 stores. No LDS, no barrier.
#pragma unroll
    for (int off = 32; off > 0; off >>= 1)
        local += __shfl_xor(local, off, 64);
    if (lane == 0)
        partials[bid * 4 + wave] = local;
}

// Kernel 3: reduce 65536 per-wave partials -> out[0]. One block, ~5 us.
__global__ __launch_bounds__(1024) void reduce_kernel(
    const float* __restrict__ partials, float* __restrict__ out, int N)
{
    __shared__ float red[16];
    const int tid  = threadIdx.x;
    const int wave = tid >> 6;
    const int lane = tid & 63;
    float s = 0.0f;
#pragma unroll 4
    for (int i = tid; i < NPART; i += 1024)
        s += partials[i];
#pragma unroll
    for (int off = 32; off > 0; off >>= 1)
        s += __shfl_xor(s, off, 64);
    if (lane == 0) red[wave] = s;
    __syncthreads();
    if (tid == 0) {
        float t = 0.0f;
#pragma unroll
        for (int w = 0; w < 16; ++w) t += red[w];
        out[0] = t * (LN2 / (float)N);
    }
}

extern "C" void kernel_launch(void* const* d_in, const int* in_sizes, int n_in,
                              void* d_out, int out_size, void* d_ws, size_t ws_size,
                              hipStream_t stream) {
    const float* img = (const float*)d_in[0];
    const float* txt = (const float*)d_in[1];
    const float* tp  = (const float*)d_in[2];
    const float* bs  = (const float*)d_in[3];
    float* out = (float*)d_out;
    int N = in_sizes[0] / D_DIM;    // 16384

    unsigned char* Ab = (unsigned char*)d_ws;       // 4 MB (k-major strips)
    unsigned char* Bb = Ab + (size_t)N * D_DIM;     // +4 MB
    float* partials   = (float*)(Bb + (size_t)N * D_DIM);   // 256 KB

    norm_cast_kernel<<<(2 * N) / 64, 256, 0, stream>>>(img, txt, Ab, Bb, N);
    siglip_loss_kernel<<<NBLK, 256, 0, stream>>>(Ab, Bb, tp, bs, partials, N);
    reduce_kernel<<<1, 1024, 0, stream>>>(partials, out, N);
}